// Round 11
// baseline (828.252 us; speedup 1.0000x reference)
//
#include <hip/hip_runtime.h>

#define NN 50000
#define NE 1600000
#define DIM 256
#define OUTD 64
#define ALPHA 0.2f

#define BSH 6                 // bucket = src >> 6 (64 nodes/bucket)
#define NBK ((NN + 63) >> 6)  // 782 buckets
#define P1 500                // binning blocks
#define EPB (NE / P1)         // 3200 edges per block (exact, div by 4)
#define TOT (NBK * P1)        // 391000 (p,b) pairs
#define S1B ((TOT + 255) / 256)  // 1528 scan blocks

#define GEMM_BLOCKS ((NN + 63) / 64)  // 782
#define WSTRIDE 264           // Wt LDS row stride in bf16

typedef unsigned short u16;
typedef unsigned int u32;
typedef __attribute__((ext_vector_type(8))) short short8;
typedef __attribute__((ext_vector_type(4))) float floatx4;

__device__ __forceinline__ u16 f2bf(float f) {
  u32 b = __float_as_uint(f);
  b += 0x7FFFu + ((b >> 16) & 1u);  // RNE
  return (u16)(b >> 16);
}
__device__ __forceinline__ float bflo(u32 u) { return __uint_as_float(u << 16); }
__device__ __forceinline__ float bfhi(u32 u) { return __uint_as_float(u & 0xFFFF0000u); }

// ---------------------------------------------------------------------------
// One-time W transpose+cast to bf16 pairs: wt[n*128+kp] = {k=2kp, k=2kp+1}.
// ---------------------------------------------------------------------------
__global__ __launch_bounds__(256) void wt_kernel(const float* __restrict__ W,
                                                 u32* __restrict__ wt) {
  const int g = blockIdx.x * 256 + threadIdx.x;  // 0..8191
  const int n = g >> 7;
  const int kp = g & 127;
  const float lo = W[(size_t)(2 * kp) * OUTD + n];
  const float hi = W[(size_t)(2 * kp + 1) * OUTD + n];
  wt[g] = (u32)f2bf(lo) | ((u32)f2bf(hi) << 16);
}

// ---------------------------------------------------------------------------
// h = x @ W via bf16 MFMA (fp32 accum) -> packed bf16 hb; s1/s2 in epilogue.
// ---------------------------------------------------------------------------
__global__ __launch_bounds__(256) void gemm_h_kernel(
    const float* __restrict__ x, const u32* __restrict__ wt,
    const float* __restrict__ a, u16* __restrict__ hb,
    float* __restrict__ s1, float* __restrict__ s2)
{
  __shared__ u16 Wl[OUTD * WSTRIDE];  // 33 KB
  const int t = threadIdx.x;
  {
    const uint4* srcv = (const uint4*)wt;
#pragma unroll
    for (int i = 0; i < 8; ++i) {
      const int c = t + 256 * i;
      const int n = c >> 5;
      const int k8 = c & 31;
      *(uint4*)&Wl[n * WSTRIDE + k8 * 8] = srcv[c];
    }
  }
  __syncthreads();

  const int lane = t & 63;
  const int wv = t >> 6;
  const int n = lane & 15;
  const int quad = lane >> 4;
  int rb = blockIdx.x * 64 + wv * 16;
  if (rb > NN - 16) rb = NN - 16;  // tail clamp (duplicates benign)
  const int row = rb + n;
  const float4* xrow = (const float4*)(x + (size_t)row * DIM);

  floatx4 acc[4] = {{0.f, 0.f, 0.f, 0.f},
                    {0.f, 0.f, 0.f, 0.f},
                    {0.f, 0.f, 0.f, 0.f},
                    {0.f, 0.f, 0.f, 0.f}};

#pragma unroll
  for (int kk = 0; kk < 8; ++kk) {
    const float4 lo = xrow[kk * 8 + quad * 2];
    const float4 hi = xrow[kk * 8 + quad * 2 + 1];
    union { u32 u[4]; short8 s; } af;
    af.u[0] = (u32)f2bf(lo.x) | ((u32)f2bf(lo.y) << 16);
    af.u[1] = (u32)f2bf(lo.z) | ((u32)f2bf(lo.w) << 16);
    af.u[2] = (u32)f2bf(hi.x) | ((u32)f2bf(hi.y) << 16);
    af.u[3] = (u32)f2bf(hi.z) | ((u32)f2bf(hi.w) << 16);
#pragma unroll
    for (int nt = 0; nt < 4; ++nt) {
      const short8 bf =
          *(const short8*)&Wl[(nt * 16 + n) * WSTRIDE + kk * 32 + quad * 8];
      acc[nt] = __builtin_amdgcn_mfma_f32_16x16x32_bf16(af.s, bf, acc[nt], 0, 0, 0);
    }
  }

  float av1[4], av2[4];
#pragma unroll
  for (int nt = 0; nt < 4; ++nt) {
    av1[nt] = a[nt * 16 + n];
    av2[nt] = a[OUTD + nt * 16 + n];
  }

#pragma unroll
  for (int reg = 0; reg < 4; ++reg) {
    const int r = rb + quad * 4 + reg;
    float q1 = acc[0][reg] * av1[0] + acc[1][reg] * av1[1] +
               acc[2][reg] * av1[2] + acc[3][reg] * av1[3];
    float q2 = acc[0][reg] * av2[0] + acc[1][reg] * av2[1] +
               acc[2][reg] * av2[2] + acc[3][reg] * av2[3];
#pragma unroll
    for (int off = 1; off <= 8; off <<= 1) {
      q1 += __shfl_xor(q1, off);
      q2 += __shfl_xor(q2, off);
    }
    if (n == 0) { s1[r] = q1; s2[r] = q2; }
#pragma unroll
    for (int nt = 0; nt < 4; ++nt)
      hb[(size_t)r * OUTD + nt * 16 + n] = f2bf(acc[nt][reg]);
  }
}

// ---------------------------------------------------------------------------
// Per-block bucket histogram (782 buckets -> low LDS-atomic contention).
// ---------------------------------------------------------------------------
__global__ __launch_bounds__(256) void hist_kernel(const int* __restrict__ src,
                                                   int* __restrict__ bcnt) {
  __shared__ int lh[NBK];
  const int t = threadIdx.x;
  for (int i = t; i < NBK; i += 256) lh[i] = 0;
  __syncthreads();
  const int4* src4 = (const int4*)(src + blockIdx.x * EPB);
  for (int i = t; i < EPB / 4; i += 256) {
    const int4 s = src4[i];
    atomicAdd(&lh[s.x >> BSH], 1);
    atomicAdd(&lh[s.y >> BSH], 1);
    atomicAdd(&lh[s.z >> BSH], 1);
    atomicAdd(&lh[s.w >> BSH], 1);
  }
  __syncthreads();
  for (int i = t; i < NBK; i += 256)
    bcnt[(size_t)blockIdx.x * NBK + i] = lh[i];
}

// ---------------------------------------------------------------------------
// Exclusive scan of bcnt in b-major order (e = b*P1 + p); global offset of
// element e is binoff[e] + bsums[e>>8] (consumers add bsums inline; no scan3).
// ---------------------------------------------------------------------------
__global__ __launch_bounds__(256) void scan1_kernel(const int* __restrict__ bcnt,
                                                    int* __restrict__ binoff,
                                                    int* __restrict__ bsums) {
  __shared__ int tmp[256];
  const int t = threadIdx.x;
  const int e = blockIdx.x * 256 + t;
  int v = 0;
  if (e < TOT) {
    const int b = e / P1;
    const int p = e - b * P1;
    v = bcnt[(size_t)p * NBK + b];
  }
  int x = v;
  tmp[t] = v;
  __syncthreads();
  for (int off = 1; off < 256; off <<= 1) {
    const int y = (t >= off) ? tmp[t - off] : 0;
    __syncthreads();
    x += y;
    tmp[t] = x;
    __syncthreads();
  }
  if (e < TOT) binoff[e] = x - v;
  if (t == 255) bsums[blockIdx.x] = x;
}

__global__ __launch_bounds__(1024) void scan2_kernel(int* __restrict__ bsums) {
  __shared__ int tmp[1024];
  const int t = threadIdx.x;
  const int v0 = (2 * t < S1B) ? bsums[2 * t] : 0;
  const int v1 = (2 * t + 1 < S1B) ? bsums[2 * t + 1] : 0;
  const int s = v0 + v1;
  int x = s;
  tmp[t] = s;
  __syncthreads();
  for (int off = 1; off < 1024; off <<= 1) {
    const int y = (t >= off) ? tmp[t - off] : 0;
    __syncthreads();
    x += y;
    tmp[t] = x;
    __syncthreads();
  }
  const int base = x - s;  // exclusive
  if (2 * t < S1B) bsums[2 * t] = base;
  if (2 * t + 1 < S1B) bsums[2 * t + 1] = base + v0;
}

// ---------------------------------------------------------------------------
// Binning into block-private ranges. packed = (src&63)<<16 | dst.
// ---------------------------------------------------------------------------
__global__ __launch_bounds__(256) void bin_kernel(const int* __restrict__ src,
                                                  const int* __restrict__ dst,
                                                  const int* __restrict__ binoff,
                                                  const int* __restrict__ bsums,
                                                  u32* __restrict__ binned) {
  __shared__ int lcur[NBK];
  const int t = threadIdx.x;
  for (int b = t; b < NBK; b += 256) {
    const int e = b * P1 + blockIdx.x;
    lcur[b] = binoff[e] + bsums[e >> 8];
  }
  __syncthreads();
  const int4* src4 = (const int4*)(src + blockIdx.x * EPB);
  const int4* dst4 = (const int4*)(dst + blockIdx.x * EPB);
  for (int i = t; i < EPB / 4; i += 256) {
    const int4 s = src4[i];
    const int4 d = dst4[i];
    int pos;
    pos = atomicAdd(&lcur[s.x >> BSH], 1);
    binned[pos] = ((u32)(s.x & 63) << 16) | (u32)d.x;
    pos = atomicAdd(&lcur[s.y >> BSH], 1);
    binned[pos] = ((u32)(s.y & 63) << 16) | (u32)d.y;
    pos = atomicAdd(&lcur[s.z >> BSH], 1);
    binned[pos] = ((u32)(s.z & 63) << 16) | (u32)d.z;
    pos = atomicAdd(&lcur[s.w >> BSH], 1);
    binned[pos] = ((u32)(s.w & 63) << 16) | (u32)d.w;
  }
}

// ---------------------------------------------------------------------------
// Fused CSR+aggregation: one block per 64-node bucket. LDS fp32 accumulators
// acc[64][68] (padded stride -> banks spread) + wsum[64]; stream the bucket's
// binned edges, 8-edge groups gather hb rows (uint4 = 8 bf16 dims/lane) and
// ds_add_f32 into the owning node's row. No edst materialization, no per-node
// CSR. Waves free-run (atomics make ordering irrelevant); one barrier total.
// ---------------------------------------------------------------------------
__global__ __launch_bounds__(256) void agg2_kernel(
    const u16* __restrict__ hb, const float* __restrict__ s1,
    const float* __restrict__ s2, const int* __restrict__ binoff,
    const int* __restrict__ bsums, const u32* __restrict__ binned,
    float* __restrict__ out)
{
  __shared__ float accf[64][68];  // 17.4 KB
  __shared__ float ws[64];
  __shared__ float s1l[64];
  const int b = blockIdx.x;
  const int t = threadIdx.x;

  const int e0 = b * P1;
  const int beg = binoff[e0] + bsums[e0 >> 8];
  int end = NE;
  if (b < NBK - 1) {
    const int e1 = e0 + P1;
    end = binoff[e1] + bsums[e1 >> 8];
  }

  for (int i = t; i < 64 * 68; i += 256) ((float*)accf)[i] = 0.f;
  if (t < 64) {
    ws[t] = 0.f;
    const int node = (b << BSH) + t;
    s1l[t] = (node < NN) ? s1[node] : 0.f;
  }
  __syncthreads();

  const int lane = t & 63;
  const int wv = t >> 6;
  const int g = lane >> 3;
  const int seg = lane & 7;

  for (int c0 = beg + wv * 64; c0 < end; c0 += 256) {
    const int m = min(64, end - c0);
    int d = 0, sl = 0;
    float w = 0.f;
    if (lane < m) {
      const u32 p = binned[c0 + lane];
      d = (int)(p & 0xFFFFu);
      sl = (int)((p >> 16) & 63u);
      const float logit = s1l[sl] + s2[d];
      const float lr = logit > 0.f ? logit : ALPHA * logit;
      w = __expf(-lr);
    }
#pragma unroll 4
    for (int e = 0; e < m; e += 8) {
      const int idx = e + g;               // <= 63
      const int dg = __shfl(d, idx);
      const float wg = __shfl(w, idx);     // 0 for tail lanes
      const int slg = __shfl(sl, idx);
      const uint4 p = *(const uint4*)&hb[(size_t)dg * OUTD + seg * 8];
      float* arow = &accf[slg][seg * 8];
      atomicAdd(&arow[0], wg * bflo(p.x));
      atomicAdd(&arow[1], wg * bfhi(p.x));
      atomicAdd(&arow[2], wg * bflo(p.y));
      atomicAdd(&arow[3], wg * bfhi(p.y));
      atomicAdd(&arow[4], wg * bflo(p.z));
      atomicAdd(&arow[5], wg * bfhi(p.z));
      atomicAdd(&arow[6], wg * bflo(p.w));
      atomicAdd(&arow[7], wg * bfhi(p.w));
      if (seg == 0) atomicAdd(&ws[slg], wg);
    }
  }
  __syncthreads();

  // epilogue: wave wv -> nodes wv*16..wv*16+15, lane = dim
  for (int j = 0; j < 16; ++j) {
    const int n = wv * 16 + j;
    const int node = (b << BSH) + n;
    if (node < NN) {
      const float wsv = ws[n];
      const float inv = wsv > 0.f ? 1.f / wsv : 0.f;
      const float v = accf[n][lane] * inv;
      out[(size_t)node * OUTD + lane] = v > 0.f ? v : (__expf(v) - 1.f);
    }
  }
}

// ---------------------------------------------------------------------------
extern "C" void kernel_launch(void* const* d_in, const int* in_sizes, int n_in,
                              void* d_out, int out_size, void* d_ws, size_t ws_size,
                              hipStream_t stream) {
  const float* x = (const float*)d_in[0];
  const int* ei = (const int*)d_in[1];
  const float* W = (const float*)d_in[2];
  const float* a = (const float*)d_in[3];
  float* out = (float*)d_out;

  // workspace layout (~17 MB)
  u16* hb = (u16*)d_ws;                   // NN*64 bf16 (6.4 MB)
  float* s1 = (float*)(hb + (size_t)NN * OUTD);  // NN
  float* s2 = s1 + NN;                    // NN
  int* bcnt = (int*)(s2 + NN);            // TOT
  int* binoff = bcnt + TOT;               // TOT
  int* bsums = binoff + TOT;              // S1B
  u32* binned = (u32*)(bsums + S1B);      // NE
  u32* wt = (u32*)(binned + NE);          // 8192 (32 KB W^T bf16)

  const int* src = ei;
  const int* dst = ei + NE;

  hipLaunchKernelGGL(wt_kernel, dim3(32), dim3(256), 0, stream, W, wt);
  hipLaunchKernelGGL(gemm_h_kernel, dim3(GEMM_BLOCKS), dim3(256), 0, stream,
                     x, wt, a, hb, s1, s2);
  hipLaunchKernelGGL(hist_kernel, dim3(P1), dim3(256), 0, stream, src, bcnt);
  hipLaunchKernelGGL(scan1_kernel, dim3(S1B), dim3(256), 0, stream,
                     bcnt, binoff, bsums);
  hipLaunchKernelGGL(scan2_kernel, dim3(1), dim3(1024), 0, stream, bsums);
  hipLaunchKernelGGL(bin_kernel, dim3(P1), dim3(256), 0, stream,
                     src, dst, binoff, bsums, binned);
  hipLaunchKernelGGL(agg2_kernel, dim3(NBK), dim3(256), 0, stream,
                     hb, s1, s2, binoff, bsums, binned, out);
}